// Round 6
// baseline (111.638 us; speedup 1.0000x reference)
//
#include <hip/hip_runtime.h>
#include <hip/hip_bf16.h>

#define B_ 4
#define H_ 4
#define N_ 4096
#define D_ 64
#define E_ 256
#define KVB 64
#define QBLK 128            // per block: 4 waves x 32 q-rows
#define NT (N_ / KVB)

typedef short short8 __attribute__((ext_vector_type(8)));
typedef float f32x4 __attribute__((ext_vector_type(4)));
typedef float f32x16 __attribute__((ext_vector_type(16)));

__device__ __forceinline__ ushort f2bf(float f) {
  union { float f; unsigned u; } a; a.f = f;
  unsigned r = a.u + 0x7fffu + ((a.u >> 16) & 1u);
  return (ushort)(r >> 16);
}

__device__ __forceinline__ uint4 pack8(float a0, float a1, float a2, float a3,
                                       float a4, float a5, float a6, float a7) {
  uint4 u;
  u.x = (unsigned)f2bf(a0) | ((unsigned)f2bf(a1) << 16);
  u.y = (unsigned)f2bf(a2) | ((unsigned)f2bf(a3) << 16);
  u.z = (unsigned)f2bf(a4) | ((unsigned)f2bf(a5) << 16);
  u.w = (unsigned)f2bf(a6) | ((unsigned)f2bf(a7) << 16);
  return u;
}

__device__ __forceinline__ unsigned cvt_pk_bf16(float lo, float hi) {
  unsigned r;
  asm("v_cvt_pk_bf16_f32 %0, %1, %2" : "=v"(r) : "v"(lo), "v"(hi));
  return r;
}

__device__ __forceinline__ void permlane32_swap(unsigned &a, unsigned &b) {
  asm volatile("v_permlane32_swap_b32 %0, %1" : "+v"(a), "+v"(b));
}

// ---------------- W cast: f32 -> bf16 ----------------
__global__ void cast_w_kernel(const float* __restrict__ W, ushort* __restrict__ Wb) {
  int i = blockIdx.x * blockDim.x + threadIdx.x;
  float4 x = ((const float4*)W)[i];
  ushort4 o;
  o.x = f2bf(x.x); o.y = f2bf(x.y); o.z = f2bf(x.z); o.w = f2bf(x.w);
  ((ushort4*)Wb)[i] = o;
}

// ---------------- Pre-pass: emit K and V^T tiles in MFMA-FRAGMENT order ----------------
// Chunk u in [0,512) of a tile: frag = u>>6 (nb/db*4 + ks), lane = u&63.
//  K  chunk u = K[kv = (frag>>2)*32 + (lane&31)][d  = (frag&3)*16 + ((lane>>5)&1)*8 + 0..7]
//  Vt chunk u = V[kv0..kv0+7][d = (frag>>2)*32 + (lane&31)], kv0 = (frag&3)*16 + ((lane>>5)&1)*8
__global__ void prep_kv(const float* __restrict__ k, const float* __restrict__ v,
                        ushort* __restrict__ Kb, ushort* __restrict__ Vtb) {
  __shared__ float vt[64][65];
  const int gid = blockIdx.x;            // bh*NT + t
  const int bh = gid >> 6, t = gid & 63;
  const int b = bh >> 2, h = bh & 3;
  const int tid = threadIdx.x;
  const int rr = tid >> 4, cc = (tid & 15) * 4;
  const float* kg = k + ((size_t)b * N_ + t * 64) * E_ + h * 64;
  const float* vg = v + ((size_t)b * N_ + t * 64) * E_ + h * 64;
  ushort* ko = Kb + (size_t)gid * 4096;
  ushort* vo = Vtb + (size_t)gid * 4096;

  for (int it = 0; it < 4; ++it) {
    int r = rr + it * 16;
    float4 vx = *(const float4*)(vg + (size_t)r * E_ + cc);
    vt[r][cc] = vx.x; vt[r][cc + 1] = vx.y; vt[r][cc + 2] = vx.z; vt[r][cc + 3] = vx.w;
  }
  __syncthreads();

  for (int j = 0; j < 2; ++j) {
    int u = j * 256 + tid;
    int frag = u >> 6, l = u & 63;
    int a = (frag >> 2) * 32 + (l & 31);
    int c0 = (frag & 3) * 16 + ((l >> 5) & 1) * 8;
    // K chunk: row a, cols c0..c0+7
    {
      const float* p = kg + (size_t)a * E_ + c0;
      float4 x0 = *(const float4*)(p);
      float4 x1 = *(const float4*)(p + 4);
      *(uint4*)(ko + u * 8) = pack8(x0.x, x0.y, x0.z, x0.w, x1.x, x1.y, x1.z, x1.w);
    }
    // V^T chunk: col a (=d), rows c0..c0+7
    {
      *(uint4*)(vo + u * 8) = pack8(vt[c0][a], vt[c0 + 1][a], vt[c0 + 2][a], vt[c0 + 3][a],
                                    vt[c0 + 4][a], vt[c0 + 5][a], vt[c0 + 6][a], vt[c0 + 7][a]);
    }
  }
}

// ---------------- Flash attention: 4 waves x 32 q-rows, frag-linear LDS, in-register softmax ----------------
__launch_bounds__(256, 2)
__global__ void attn_kernel(const float* __restrict__ q,
                            const ushort* __restrict__ Kb,
                            const ushort* __restrict__ Vtb,
                            ushort* __restrict__ X) {
  __shared__ __attribute__((aligned(16))) ushort Ks[2][4096];
  __shared__ __attribute__((aligned(16))) ushort Vs[2][4096];
  __shared__ float Lb[4][32];

  const int bid = blockIdx.x;
  const int swz = (bid & 7) * 64 + (bid >> 3);   // 512 blocks, bijective, XCD-contiguous
  const int bh = swz >> 5;
  const int qt = swz & 31;
  const int b = bh >> 2, h = bh & 3;
  const int tid = threadIdx.x;
  const int wid = tid >> 6;
  const int lane = tid & 63;
  const int ln = lane & 31;      // 32x32 MFMA row/col lane id
  const int hi = lane >> 5;      // k-slice half

  const char* Kg = (const char*)Kb + (size_t)bh * NT * 8192;
  const char* Vg = (const char*)Vtb + (size_t)bh * NT * 8192;

  // ---- Q B-fragments (col = q-row = ln), scale*log2e folded ----
  const float SC = 0.125f * 1.44269504f;
  const int qrow0 = qt * QBLK + wid * 32;
  const float* Qg = q + ((size_t)b * N_ + qrow0 + ln) * E_ + h * D_;
  short8 qf[4];
#pragma unroll
  for (int ks = 0; ks < 4; ++ks) {
    const float* p = Qg + ks * 16 + hi * 8;
    float4 x0 = *(const float4*)(p);
    float4 x1 = *(const float4*)(p + 4);
    short8 f;
    f[0] = (short)f2bf(x0.x * SC); f[1] = (short)f2bf(x0.y * SC);
    f[2] = (short)f2bf(x0.z * SC); f[3] = (short)f2bf(x0.w * SC);
    f[4] = (short)f2bf(x1.x * SC); f[5] = (short)f2bf(x1.y * SC);
    f[6] = (short)f2bf(x1.z * SC); f[7] = (short)f2bf(x1.w * SC);
    qf[ks] = f;
  }

  f32x16 O0 = (f32x16)0.0f, O1 = (f32x16)0.0f;
  float lsum = 0.f;

  // ---- prologue: stage tile 0 (chunks tid and tid+256; linear both sides) ----
  {
    uint4 k0 = *(const uint4*)(Kg + tid * 16);
    uint4 k1 = *(const uint4*)(Kg + 4096 + tid * 16);
    uint4 v0 = *(const uint4*)(Vg + tid * 16);
    uint4 v1 = *(const uint4*)(Vg + 4096 + tid * 16);
    *(uint4*)((char*)Ks[0] + tid * 16) = k0;
    *(uint4*)((char*)Ks[0] + 4096 + tid * 16) = k1;
    *(uint4*)((char*)Vs[0] + tid * 16) = v0;
    *(uint4*)((char*)Vs[0] + 4096 + tid * 16) = v1;
  }
  __syncthreads();
  int cur = 0;

  for (int t = 0; t < NT; ++t) {
    const bool pfn = (t + 1 < NT);
    uint4 rk0, rk1, rv0, rv1;
    if (pfn) {
      const char* kg = Kg + (size_t)(t + 1) * 8192;
      const char* vg = Vg + (size_t)(t + 1) * 8192;
      rk0 = *(const uint4*)(kg + tid * 16);
      rk1 = *(const uint4*)(kg + 4096 + tid * 16);
      rv0 = *(const uint4*)(vg + tid * 16);
      rv1 = *(const uint4*)(vg + 4096 + tid * 16);
    }

    // ---- K A-fragments: frag-linear reads (immediate offsets, conflict-free) ----
    short8 kf[2][4];
#pragma unroll
    for (int nb = 0; nb < 2; ++nb)
#pragma unroll
      for (int ks = 0; ks < 4; ++ks)
        kf[nb][ks] = *(short8*)((char*)Ks[cur] + (nb * 4 + ks) * 1024 + lane * 16);

    // ---- S^T = K Q^T : D[row=kv][col=q] ----
    f32x16 S0 = (f32x16)0.0f, S1 = (f32x16)0.0f;
    __builtin_amdgcn_s_setprio(1);
#pragma unroll
    for (int ks = 0; ks < 4; ++ks) {
      S0 = __builtin_amdgcn_mfma_f32_32x32x16_bf16(kf[0][ks], qf[ks], S0, 0, 0, 0);
      S1 = __builtin_amdgcn_mfma_f32_32x32x16_bf16(kf[1][ks], qf[ks], S1, 0, 0, 0);
    }
    __builtin_amdgcn_s_setprio(0);

    // ---- P = 2^S in-register; tree-structured per-lane row sum (row = q = ln) ----
    float p[32];
#pragma unroll
    for (int i = 0; i < 16; ++i) {
      p[i]      = __builtin_amdgcn_exp2f(S0[i]);
      p[16 + i] = __builtin_amdgcn_exp2f(S1[i]);
    }
    {
      float s1[16];
#pragma unroll
      for (int i = 0; i < 16; ++i) s1[i] = p[2 * i] + p[2 * i + 1];
#pragma unroll
      for (int i = 0; i < 8; ++i) s1[i] = s1[2 * i] + s1[2 * i + 1];
#pragma unroll
      for (int i = 0; i < 4; ++i) s1[i] = s1[2 * i] + s1[2 * i + 1];
      lsum += (s1[0] + s1[1]) + (s1[2] + s1[3]);
    }

    // ---- pack P -> PV A-fragments via cvt_pk + permlane32_swap (T12) ----
    short8 pa[4];
#pragma unroll
    for (int nb = 0; nb < 2; ++nb)
#pragma unroll
      for (int ksp = 0; ksp < 2; ++ksp) {
        int base = nb * 16 + ksp * 8;
        unsigned w0 = cvt_pk_bf16(p[base + 0], p[base + 1]);
        unsigned w2 = cvt_pk_bf16(p[base + 4], p[base + 5]);
        permlane32_swap(w0, w2);
        unsigned w1 = cvt_pk_bf16(p[base + 2], p[base + 3]);
        unsigned w3 = cvt_pk_bf16(p[base + 6], p[base + 7]);
        permlane32_swap(w1, w3);
        uint4 u; u.x = w0; u.y = w1; u.z = w2; u.w = w3;
        union { uint4 u4; short8 s8; } cv; cv.u4 = u;
        pa[nb * 2 + ksp] = cv.s8;
      }

    // ---- write staged regs into the other buffer (its readers finished last iter) ----
    if (pfn) {
      *(uint4*)((char*)Ks[cur ^ 1] + tid * 16) = rk0;
      *(uint4*)((char*)Ks[cur ^ 1] + 4096 + tid * 16) = rk1;
      *(uint4*)((char*)Vs[cur ^ 1] + tid * 16) = rv0;
      *(uint4*)((char*)Vs[cur ^ 1] + 4096 + tid * 16) = rv1;
    }

    // ---- V B-fragments: frag-linear reads ----
    short8 vf[2][4];
#pragma unroll
    for (int db = 0; db < 2; ++db)
#pragma unroll
      for (int ks = 0; ks < 4; ++ks)
        vf[db][ks] = *(short8*)((char*)Vs[cur] + (db * 4 + ks) * 1024 + lane * 16);

    // ---- O += P V : D[row=q][col=d] ----
    __builtin_amdgcn_s_setprio(1);
#pragma unroll
    for (int ks = 0; ks < 4; ++ks) {
      O0 = __builtin_amdgcn_mfma_f32_32x32x16_bf16(pa[ks], vf[0][ks], O0, 0, 0, 0);
      O1 = __builtin_amdgcn_mfma_f32_32x32x16_bf16(pa[ks], vf[1][ks], O1, 0, 0, 0);
    }
    __builtin_amdgcn_s_setprio(0);

    __syncthreads();
    cur ^= 1;
  }

  // ---- epilogue: full row sums, normalize, write X[b][n][e] ----
  float l = lsum + __shfl_xor(lsum, 32);
  if (lane < 32) Lb[wid][lane] = l;
  asm volatile("" ::: "memory");
  float inv[16];
#pragma unroll
  for (int r = 0; r < 16; ++r)
    inv[r] = 1.0f / Lb[wid][(r & 3) + 8 * (r >> 2) + 4 * hi];

  ushort* Xp = X + ((size_t)b * N_) * E_ + h * D_;
#pragma unroll
  for (int r = 0; r < 16; ++r) {
    int qrow = qrow0 + (r & 3) + 8 * (r >> 2) + 4 * hi;
    Xp[(size_t)qrow * E_ + ln]      = f2bf(O0[r] * inv[r]);
    Xp[(size_t)qrow * E_ + 32 + ln] = f2bf(O1[r] * inv[r]);
  }
}

// ---------------- Output projection: out = X @ W^T + b ----------------
__launch_bounds__(256, 2)
__global__ void proj_kernel(const ushort* __restrict__ X, const ushort* __restrict__ Wb,
                            const float* __restrict__ bias, float* __restrict__ out) {
  const int m0   = blockIdx.x * 64;
  const int tid  = threadIdx.x;
  const int wid  = tid >> 6;
  const int lane = tid & 63;
  const int g    = lane >> 4;
  const int lr   = lane & 15;
  const int n0   = wid * 64;

  f32x4 acc[4][4];
  for (int mb = 0; mb < 4; ++mb)
    for (int nb = 0; nb < 4; ++nb)
      acc[mb][nb] = (f32x4){0.f, 0.f, 0.f, 0.f};

  for (int k0 = 0; k0 < E_; k0 += 32) {
    short8 af[4], bfr[4];
    for (int mb = 0; mb < 4; ++mb)
      af[mb] = *(const short8*)(X + (size_t)(m0 + mb * 16 + lr) * E_ + k0 + g * 8);
    for (int nb = 0; nb < 4; ++nb)
      bfr[nb] = *(const short8*)(Wb + (size_t)(n0 + nb * 16 + lr) * E_ + k0 + g * 8);
    for (int mb = 0; mb < 4; ++mb)
      for (int nb = 0; nb < 4; ++nb)
        acc[mb][nb] = __builtin_amdgcn_mfma_f32_16x16x32_bf16(af[mb], bfr[nb], acc[mb][nb], 0, 0, 0);
  }

  for (int nb = 0; nb < 4; ++nb) {
    float bv = bias[n0 + nb * 16 + lr];
    for (int mb = 0; mb < 4; ++mb)
      for (int r = 0; r < 4; ++r)
        out[(size_t)(m0 + mb * 16 + g * 4 + r) * E_ + n0 + nb * 16 + lr] = acc[mb][nb][r] + bv;
  }
}

extern "C" void kernel_launch(void* const* d_in, const int* in_sizes, int n_in,
                              void* d_out, int out_size, void* d_ws, size_t ws_size,
                              hipStream_t stream) {
  const float* q    = (const float*)d_in[0];
  const float* k    = (const float*)d_in[1];
  const float* v    = (const float*)d_in[2];
  const float* W    = (const float*)d_in[3];
  const float* bias = (const float*)d_in[4];

  char* ws = (char*)d_ws;
  ushort* X   = (ushort*)ws;                                  // 8 MiB
  ushort* Wb  = (ushort*)(ws + 8388608);                      // 128 KiB
  ushort* Kb  = (ushort*)(ws + 8388608 + 131072);             // 8 MiB
  ushort* Vtb = (ushort*)(ws + 8388608 + 131072 + 8388608);   // 8 MiB

  cast_w_kernel<<<64, 256, 0, stream>>>(W, Wb);
  prep_kv<<<B_ * H_ * NT, 256, 0, stream>>>(k, v, Kb, Vtb);
  attn_kernel<<<B_ * H_ * (N_ / QBLK), 256, 0, stream>>>(q, Kb, Vtb, X);
  proj_kernel<<<(B_ * N_) / 64, 256, 0, stream>>>(X, Wb, bias, (float*)d_out);
}